// Round 19
// baseline (131.231 us; speedup 1.0000x reference)
//
#include <hip/hip_runtime.h>
#include <math.h>

// RecurNN: B=256, L=256, E=100, T=255.
// x_t = W1L*left_t + W1R*right_t + b1; h_t = tanh(x_t); out = sigmoid(W2 h_254 + b2).
// These inputs: right_t always a leaf; left_t = node t-1 (leaf only at t=0).
//
// R19 = R18 (k-split both roles, 130us) + two fixes:
//  1. Partial arrays back to [slot][q][r] stride-1 layout (R16-proven
//     conflict-free; R18's [r][4] layout caused 5.2M bank-conflict cycles).
//     Finalize reads 4+4 stride-1 b32 instead of 2 b128.
//  2. cpart read hoisted BEFORE CMALL (data is >=3 ticks old; 8-deep ring
//     makes it race-free) -> its LDS latency hides under the fma stream
//     instead of sitting on the post-barrier critical chain.
// Structure: waves 0..3 consumers (k-slice [25q,25q+25), rows (l,l+50) per
// lane, 50 weight VGPRs, RL broadcast from own vh); waves 4..7 producers
// (k-quarter of c[t]=b1+W1R*emb, emb quarter ping-pong 2 ticks ahead).
// One "lgkmcnt(0); s_barrier" per tick; setprio(1) on consumer critical path.

#define Bc 256
#define Lc 256
#define Ec 100
#define Tc 255
#define W1cols 200

#define RL(v, k) __int_as_float(__builtin_amdgcn_readlane(__float_as_int(v), (k)))
#define RF(x)    __builtin_amdgcn_readfirstlane(x)

// ---- 25 weight pairs (50 named scalars) per wave, both roles ----
#define REP25(X) X(0) X(1) X(2) X(3) X(4) X(5) X(6) X(7) X(8) X(9) X(10) X(11) X(12) \
                 X(13) X(14) X(15) X(16) X(17) X(18) X(19) X(20) X(21) X(22) X(23) X(24)
#define DECLWC(j) float wA##j, wB##j;
#define LOADWC(j) { wA##j = rowA[j]; wB##j = rowB[j]; }
#define CM2(a,b) { const float ra_ = RL(sv,(a)), rb_ = RL(sv,(b)); \
    accA0 = fmaf(ra_, wA##a, accA0); accB0 = fmaf(ra_, wB##a, accB0); \
    accA1 = fmaf(rb_, wA##b, accA1); accB1 = fmaf(rb_, wB##b, accB1); }
#define CM1(a) { const float ra_ = RL(sv,(a)); \
    accA0 = fmaf(ra_, wA##a, accA0); accB0 = fmaf(ra_, wB##a, accB0); }
#define CMALL CM2(0,1) CM2(2,3) CM2(4,5) CM2(6,7) CM2(8,9) CM2(10,11) CM2(12,13) \
              CM2(14,15) CM2(16,17) CM2(18,19) CM2(20,21) CM2(22,23) CM1(24)

// generic fallback dot (global weights; never hot for these inputs)
__device__ __noinline__ float slow_dot(const float* rp, const float* wr) {
    float a0 = 0.f, a1 = 0.f, a2 = 0.f, a3 = 0.f;
    for (int qq = 0; qq < 25; ++qq) {
        float4 h4 = *(const float4*)(rp + 4 * qq);
        float4 w4 = *(const float4*)(wr + 4 * qq);
        a0 = fmaf(w4.x, h4.x, a0); a1 = fmaf(w4.y, h4.y, a1);
        a2 = fmaf(w4.z, h4.z, a2); a3 = fmaf(w4.w, h4.w, a3);
    }
    return (a0 + a1) + (a2 + a3);
}

__global__ __launch_bounds__(512, 2)
void fused(const int* __restrict__ token_ids,
           const int* __restrict__ comp_left,
           const int* __restrict__ comp_right,
           const float* __restrict__ emb,
           const float* __restrict__ W1,
           const float* __restrict__ b1,
           const float* __restrict__ W2,
           const float* __restrict__ b2,
           float* __restrict__ out)
{
    const int b    = blockIdx.x;
    const int tid  = threadIdx.x;          // 0..511
    const int wv   = tid >> 6;             // 0..3 consumers; 4..7 producers
    const int l    = tid & 63;
    const bool cons = (wv < 4);
    const int q    = wv & 3;               // consumer k-slice / producer k-quarter
    const int lc   = (l < 50) ? l : 49;

    __shared__ float hist[Tc * Ec];        // generic paths only
    __shared__ float part[2][4][Ec];       // cons partials, [pp][q][r] stride-1
    __shared__ float cpart[8][4][Ec];      // c partials, [slot][q][r] stride-1
    __shared__ int2  ccS[Tc];
    __shared__ int   tokRS[Tc], tokLS[Tc];
    __shared__ float red[4];

    // ---- staging ----
    for (int i = tid; i < Tc; i += 512) {
        const int cl = comp_left [b * Tc + i];
        const int cr = comp_right[b * Tc + i];
        ccS[i]   = make_int2(cl, cr);
        tokRS[i] = (cr < Lc) ? token_ids[b * Lc + cr] : -1;
        tokLS[i] = (cl < Lc) ? token_ids[b * Lc + cl] : -1;
    }

    // ---- weights: 25 pairs per wave (cons = W1L k-slice; prod = W1R k-quarter) ----
    const int kofs = (cons ? 0 : Ec) + 25 * q;
    const float* rowA = W1 + (size_t)lc * W1cols + kofs;
    const float* rowB = W1 + (size_t)(lc + 50) * W1cols + kofs;
    REP25(DECLWC)
    REP25(LOADWC)
    // producer wave 4 (q==0) carries b1
    const float b1eA = (!cons && q == 0) ? b1[lc] : 0.f;
    const float b1eB = (!cons && q == 0) ? b1[lc + 50] : 0.f;

    __syncthreads();

    // ---- state ----
    float vh = 0.f;                        // consumer lane j<25: h[25q+j]
    int2  cc = make_int2(0, 0);
    float vA0 = 0.f, vA1 = 0.f;            // producer emb-quarter ping-pong
    int   tk0 = -1, tk1 = -1;

    if (cons) {
        cc = ccS[0];
    } else {
        // ---- producer prologue: c[0], c[1] directly; issue slots for t=2,3 ----
        for (int t = 0; t < 2; ++t) {
            const int tk = RF(tokRS[t]);
            float sv = 0.f;
            if (tk >= 0 && l < 25) sv = emb[(size_t)tk * Ec + 25 * q + l];
            float accA0 = b1eA, accA1 = 0.f, accB0 = b1eB, accB1 = 0.f;
            if (tk >= 0) { CMALL }
            if (l < 50) {
                cpart[t][q][lc]      = accA0 + accA1;
                cpart[t][q][lc + 50] = accB0 + accB1;
            }
        }
        tk0 = (2 < Tc) ? RF(tokRS[2]) : -1;
        if (tk0 >= 0 && l < 25) vA0 = emb[(size_t)tk0 * Ec + 25 * q + l];
        tk1 = (3 < Tc) ? RF(tokRS[3]) : -1;
        if (tk1 >= 0 && l < 25) vA1 = emb[(size_t)tk1 * Ec + 25 * q + l];
    }

#define BARRIER asm volatile("s_waitcnt lgkmcnt(0)\n\ts_barrier" ::: "memory");

// one tick: I runtime index, PPc compile-time cons ping-pong, PAR = I&1
#define TICK(I, PPc, PAR)                                                     \
{                                                                             \
    const int i_ = (I);                                                       \
    if (cons) {                                                               \
        const int tc = i_ - 1;                                                \
        if (tc >= 0) {                                                        \
            __builtin_amdgcn_s_setprio(1);                                    \
            const int li = RF(cc.x);                                          \
            const int ri = RF(cc.y);                                          \
            /* c partials: written at tick tc-2 (>=2 barriers ago) -> read    \
               EARLY so the LDS latency hides under CMALL issue. */           \
            float cp0 = 0.f, cp1 = 0.f, cp2 = 0.f, cp3 = 0.f;                 \
            if (l < 25) {                                                     \
                const int r_ = 25 * q + l;                                    \
                cp0 = cpart[tc & 7][0][r_]; cp1 = cpart[tc & 7][1][r_];       \
                cp2 = cpart[tc & 7][2][r_]; cp3 = cpart[tc & 7][3][r_];       \
            }                                                                 \
            float sv = 0.f;                                                   \
            if (tc >= 1 && li == Lc + tc - 1) {                               \
                sv = vh;                       /* register fast path */       \
            } else if (li >= Lc) {                                            \
                const int n = li - Lc;                                        \
                if (n < tc && l < 25) sv = hist[n * Ec + 25 * q + l];         \
            } else {                                                          \
                const int tl = RF(tokLS[tc]);                                 \
                if (tl >= 0 && l < 25) sv = emb[(size_t)tl * Ec + 25 * q + l];\
            }                                                                 \
            float accA0 = 0.f, accA1 = 0.f, accB0 = 0.f, accB1 = 0.f;         \
            CMALL                                                             \
            if (l < 50) {                                                     \
                part[PPc][q][lc]      = accA0 + accA1;                        \
                part[PPc][q][lc + 50] = accB0 + accB1;                        \
            }                                                                 \
            BARRIER                                                           \
            if (l < 25) {                                                     \
                const int r = 25 * q + l;                                     \
                float x = ((part[PPc][0][r] + part[PPc][1][r]) +              \
                           (part[PPc][2][r] + part[PPc][3][r])) +             \
                          ((cp0 + cp1) + (cp2 + cp3));                        \
                if (ri >= Lc) {                                               \
                    const int n = ri - Lc;                                    \
                    if (n < tc) x += slow_dot(&hist[n * Ec],                  \
                                              W1 + (size_t)r * W1cols + Ec);  \
                }                                                             \
                const float u = __expf(2.f * x);                              \
                vh = 1.f - 2.f / (u + 1.f);    /* tanh, exact identity */     \
                hist[tc * Ec + r] = vh;        /* generic paths only */       \
            }                                                                 \
            __builtin_amdgcn_s_setprio(0);                                    \
            if (tc + 1 < Tc) cc = ccS[tc + 1];                                \
        } else {                                                              \
            BARRIER                                                           \
        }                                                                     \
    } else {                                                                  \
        const int t = i_ + 2;                                                 \
        if (t < Tc) {                                                         \
            const float sv  = (PAR) ? vA1 : vA0;   /* loaded 2 ticks ago */   \
            const int   tkc = (PAR) ? tk1 : tk0;                              \
            const int   tn  = t + 2;               /* refill this slot */     \
            const int tknew = (tn < Tc) ? RF(tokRS[tn]) : -1;                 \
            float nv = 0.f;                                                   \
            if (tknew >= 0 && l < 25) nv = emb[(size_t)tknew * Ec + 25 * q + l];\
            if (PAR) { vA1 = nv; tk1 = tknew; } else { vA0 = nv; tk0 = tknew; }\
            float accA0 = b1eA, accA1 = 0.f, accB0 = b1eB, accB1 = 0.f;       \
            if (tkc >= 0) { CMALL }                                           \
            if (l < 50) {                                                     \
                cpart[t & 7][q][lc]      = accA0 + accA1;                     \
                cpart[t & 7][q][lc + 50] = accB0 + accB1;                     \
            }                                                                 \
        }                                                                     \
        BARRIER                                                               \
    }                                                                         \
}

    // ---- main loop: 256 ticks, unroll-2 ----
    #pragma unroll 1
    for (int i2 = 0; i2 < 256; i2 += 2) {
        TICK(i2,     1, 0)
        TICK(i2 + 1, 0, 1)
    }
#undef TICK
#undef BARRIER

    // ---- out[b] = sigmoid(W2 . h_254 + b2) ----
    if (cons) {
        float pv = 0.f;
        if (l < 25) pv = W2[25 * q + l] * vh;
        #pragma unroll
        for (int off = 32; off > 0; off >>= 1) pv += __shfl_down(pv, off, 64);
        if (l == 0) red[q] = pv;
    }
    __syncthreads();
    if (tid == 0)
        out[b] = 1.f / (1.f + __expf(-((red[0] + red[1]) + (red[2] + red[3]) + b2[0])));
}

extern "C" void kernel_launch(void* const* d_in, const int* in_sizes, int n_in,
                              void* d_out, int out_size, void* d_ws, size_t ws_size,
                              hipStream_t stream) {
    const int*   token_ids  = (const int*)  d_in[0];
    const int*   comp_left  = (const int*)  d_in[1];
    const int*   comp_right = (const int*)  d_in[2];
    const float* emb        = (const float*)d_in[3];
    const float* W1         = (const float*)d_in[4];
    const float* b1         = (const float*)d_in[5];
    const float* W2         = (const float*)d_in[6];
    const float* b2         = (const float*)d_in[7];
    float*       out        = (float*)d_out;

    fused<<<Bc, 512, 0, stream>>>(token_ids, comp_left, comp_right,
                                  emb, W1, b1, W2, b2, out);
}